// Round 7
// baseline (46.263 us; speedup 1.0000x reference)
//
#include <hip/hip_runtime.h>

typedef float vf4 __attribute__((ext_vector_type(4)));

#define BATCH  8192
#define GROUPS 512
#define OUT_D  8
#define NCHUNK 8               // 64-group chunks per row

// Zero-LDS, zero-barrier design. Each wave owns 1 batch row x 64 groups.
// Half-output lane mapping: lane l computes the (l&1) half (4 floats) of
// groups gbase + l/2 and gbase + l/2 + 32. Store instruction k then writes
// out unit (l + 64k) at base + (l+64k)*16B: 1KB contiguous, full 64B lines,
// no staging. Gathers are 16B/lane; a lane pair reads adjacent halves of
// the same 32B param row (same cache line). Sort/index VALU is duplicated
// per pair (VALU is ~5% busy -- free).
__global__ __launch_bounds__(256) void hoact_kernel(
    const float* __restrict__ X,
    const float* __restrict__ P,
    float* __restrict__ out)
{
    const int chunk = blockIdx.x & (NCHUNK - 1);   // 0..7 (co-resident blocks share params)
    const int rt    = blockIdx.x >> 3;             // 4-row stripe 0..2047

    const int lane = threadIdx.x & 63;
    const int w    = threadIdx.x >> 6;

    const int row   = rt * 4 + w;
    const int gbase = chunk * 64;
    const int h     = lane & 1;        // output half
    const int gsub  = lane >> 1;       // 0..31

    const float* xrow = X + (size_t)row * (GROUPS * 3);

    #pragma unroll
    for (int s = 0; s < 2; ++s) {
        const int g = gbase + gsub + s * 32;

        // 12B of X for this group (dword loads; pairs broadcast-share)
        const float* xp = xrow + g * 3;
        float x0 = xp[0], x1 = xp[1], x2 = xp[2];

        float b0 = fabsf(x0), b1 = fabsf(x1), b2 = fabsf(x2);
        int t0 = (x0 >= 0.f) ? 1 : -1;
        int t1 = (x1 >= 0.f) ? 3 : -3;
        int t2 = (x2 >= 0.f) ? 9 : -9;
        // sort ascending by |x| (ties don't affect the result)
        if (b0 > b1) { float tb=b0; b0=b1; b1=tb; int tt=t0; t0=t1; t1=tt; }
        if (b1 > b2) { float tb=b1; b1=b2; b2=tb; int tt=t1; t1=t2; t2=tt; }
        if (b0 > b1) { float tb=b0; b0=b1; b1=tb; int tt=t0; t0=t1; t1=tt; }
        int i2 = t2 + 13;
        int i1 = t1 + t2 + 13;
        int i0 = t0 + t1 + t2 + 13;
        float c0 = b0;
        float c1 = b1 - b0;
        float c2 = b2 - b1;

        // gather only this lane's half: 16B per row, pair shares the line
        const float* pg = P + (size_t)g * (27 * OUT_D) + h * 4;
        vf4 q0 = *(const vf4*)(pg + i0 * OUT_D);
        vf4 q1 = *(const vf4*)(pg + i1 * OUT_D);
        vf4 q2 = *(const vf4*)(pg + i2 * OUT_D);

        vf4 r;
        r.x = c0*q0.x + c1*q1.x + c2*q2.x;
        r.y = c0*q0.y + c1*q1.y + c2*q2.y;
        r.z = c0*q0.z + c1*q1.z + c2*q2.z;
        r.w = c0*q0.w + c1*q1.w + c2*q2.w;

        // unit index = lane + 64*s -> 1KB contiguous per store instruction
        vf4* dst = (vf4*)(out + (size_t)row * (GROUPS * OUT_D))
                   + (size_t)chunk * 128 + (lane + 64 * s);
        __builtin_nontemporal_store(r, dst);
    }
}

extern "C" void kernel_launch(void* const* d_in, const int* in_sizes, int n_in,
                              void* d_out, int out_size, void* d_ws, size_t ws_size,
                              hipStream_t stream) {
    const float* X = (const float*)d_in[0];
    const float* P = (const float*)d_in[1];
    float* out = (float*)d_out;

    const int grid = (BATCH / 4) * NCHUNK;   // 2048 * 8 = 16384 blocks
    hoact_kernel<<<grid, 256, 0, stream>>>(X, P, out);
}

// Round 8
// 34.650 us; speedup vs baseline: 1.3352x; 1.3352x over previous
//
#include <hip/hip_runtime.h>

typedef float vf4 __attribute__((ext_vector_type(4)));

#define BATCH  8192
#define GROUPS 512
#define OUT_D  8
#define GCH    32                 // groups per block
#define NCH    (GROUPS / GCH)     // 16 chunks
#define RT     32                 // batch rows per block
#define PQ     54                 // float4 per group in P (27*8 floats = 54 units)
#define LQ     55                 // float4 per group in LDS (padded: 55%8=7 spreads bank-quads)

// Gathers moved off the L1/TA pipe onto LDS. Block stages 32 groups' params
// (27KB) once, then each wave processes 8 rows with the lane-pair mapping:
// lane l handles half (l&1) of group (l>>1) -> param gather = ds_read_b128
// (pair reads adjacent 16B halves of one 32B row), store instruction = 1KB
// contiguous nontemporal. One barrier total; 28KB LDS -> 5 blocks/CU.
__global__ __launch_bounds__(256) void hoact_kernel(
    const float* __restrict__ X,
    const float* __restrict__ P,
    float* __restrict__ out)
{
    __shared__ vf4 lp[GCH * LQ];       // 32*55*16B = 27.5 KB

    const int chunk = blockIdx.x % NCH;   // co-resident blocks share the chunk
    const int rt    = blockIdx.x / NCH;

    const int tid  = threadIdx.x;
    const int lane = tid & 63;
    const int w    = tid >> 6;
    const int gsub = lane >> 1;        // group within chunk 0..31
    const int h    = lane & 1;         // which 16B half of the param row

    // ---- stage params for this chunk: linear global read, padded LDS write ----
    const vf4* P4 = (const vf4*)P + (size_t)chunk * (GCH * PQ);
    #pragma unroll
    for (int k = 0; k < 7; ++k) {
        int m = tid + 256 * k;         // 0..1791, need < 1728
        if (m < GCH * PQ) {
            int gq = m / PQ;
            int iq = m - gq * PQ;
            lp[gq * LQ + iq] = P4[m];
        }
    }
    __syncthreads();

    const int g = chunk * GCH + gsub;
    const float* xcol = X + (size_t)g * 3;
    vf4* outb = (vf4*)out + (size_t)chunk * (GCH * OUT_D / 4) + lane;
    const size_t row_u = GROUPS * OUT_D / 4;     // 1024 units per out row

    #pragma unroll
    for (int it = 0; it < RT / 4; ++it) {
        const int row = rt * RT + w * (RT / 4) + it;

        const float* xp = xcol + (size_t)row * (GROUPS * 3);
        float x0 = xp[0], x1 = xp[1], x2 = xp[2];

        float b0 = fabsf(x0), b1 = fabsf(x1), b2 = fabsf(x2);
        int t0 = (x0 >= 0.f) ? 1 : -1;
        int t1 = (x1 >= 0.f) ? 3 : -3;
        int t2 = (x2 >= 0.f) ? 9 : -9;
        // sort ascending by |x| (ties don't affect the result)
        if (b0 > b1) { float tb=b0; b0=b1; b1=tb; int tt=t0; t0=t1; t1=tt; }
        if (b1 > b2) { float tb=b1; b1=b2; b2=tb; int tt=t1; t1=t2; t2=tt; }
        if (b0 > b1) { float tb=b0; b0=b1; b1=tb; int tt=t0; t0=t1; t1=tt; }
        int i2 = t2 + 13;
        int i1 = t1 + t2 + 13;
        int i0 = t0 + t1 + t2 + 13;
        float c0 = b0;
        float c1 = b1 - b0;
        float c2 = b2 - b1;

        // LDS gathers: unit index = gsub*55 + idx*2 + h
        const int base = gsub * LQ + h;
        vf4 q0 = lp[base + i0 * 2];
        vf4 q1 = lp[base + i1 * 2];
        vf4 q2 = lp[base + i2 * 2];

        vf4 r = c0 * q0 + c1 * q1 + c2 * q2;

        // 64 lanes -> 64 consecutive float4 units: 1KB contiguous store
        __builtin_nontemporal_store(r, outb + (size_t)row * row_u);
    }
}

extern "C" void kernel_launch(void* const* d_in, const int* in_sizes, int n_in,
                              void* d_out, int out_size, void* d_ws, size_t ws_size,
                              hipStream_t stream) {
    const float* X = (const float*)d_in[0];
    const float* P = (const float*)d_in[1];
    float* out = (float*)d_out;

    const int grid = (BATCH / RT) * NCH;   // 256 * 16 = 4096
    hoact_kernel<<<grid, 256, 0, stream>>>(X, P, out);
}

// Round 9
// 34.581 us; speedup vs baseline: 1.3378x; 1.0020x over previous
//
#include <hip/hip_runtime.h>

typedef float vf4 __attribute__((ext_vector_type(4)));

#define BATCH  8192
#define GROUPS 512
#define OUT_D  8
#define GCH    32                 // groups per block
#define NCH    (GROUPS / GCH)     // 16 chunks
#define RT     64                 // batch rows per block (16 per wave)
#define PQ     54                 // float4 per group in P (27*8 floats)
#define LQ     55                 // float4 per group in LDS (pad: 55%8=7 spreads bank-quads)

// R8 structure (LDS-gathered params, pair-split lanes, direct 1KB-contiguous
// nontemporal stores) with 2x the rows per block: staging 27KB now amortizes
// over 64KB of output instead of 32KB. One barrier per block, 27.5KB LDS ->
// 5 blocks/CU, grid 2048.
__global__ __launch_bounds__(256) void hoact_kernel(
    const float* __restrict__ X,
    const float* __restrict__ P,
    float* __restrict__ out)
{
    __shared__ vf4 lp[GCH * LQ];       // 27.5 KB

    const int chunk = blockIdx.x % NCH;   // co-resident blocks share the chunk
    const int rt    = blockIdx.x / NCH;

    const int tid  = threadIdx.x;
    const int lane = tid & 63;
    const int w    = tid >> 6;
    const int gsub = lane >> 1;        // group within chunk 0..31
    const int h    = lane & 1;         // which 16B half of the param row

    // ---- stage params for this chunk: linear L2 read, padded LDS write ----
    const vf4* P4 = (const vf4*)P + (size_t)chunk * (GCH * PQ);
    #pragma unroll
    for (int k = 0; k < 7; ++k) {
        int m = tid + 256 * k;         // 0..1791, need < 1728
        if (m < GCH * PQ) {
            int gq = m / PQ;
            int iq = m - gq * PQ;
            lp[gq * LQ + iq] = P4[m];
        }
    }
    __syncthreads();

    const int g = chunk * GCH + gsub;
    const float* xcol = X + (size_t)g * 3;
    vf4* outb = (vf4*)out + (size_t)chunk * (GCH * OUT_D / 4) + lane;
    const size_t row_u = GROUPS * OUT_D / 4;     // 1024 units per out row
    const int base = gsub * LQ + h;

    #pragma unroll
    for (int it = 0; it < RT / 4; ++it) {
        const int row = rt * RT + w * (RT / 4) + it;

        const float* xp = xcol + (size_t)row * (GROUPS * 3);
        float x0 = xp[0], x1 = xp[1], x2 = xp[2];

        float b0 = fabsf(x0), b1 = fabsf(x1), b2 = fabsf(x2);
        int t0 = (x0 >= 0.f) ? 1 : -1;
        int t1 = (x1 >= 0.f) ? 3 : -3;
        int t2 = (x2 >= 0.f) ? 9 : -9;
        // sort ascending by |x| (ties don't affect the result)
        if (b0 > b1) { float tb=b0; b0=b1; b1=tb; int tt=t0; t0=t1; t1=tt; }
        if (b1 > b2) { float tb=b1; b1=b2; b2=tb; int tt=t1; t1=t2; t2=tt; }
        if (b0 > b1) { float tb=b0; b0=b1; b1=tb; int tt=t0; t0=t1; t1=tt; }
        int i2 = t2 + 13;
        int i1 = t1 + t2 + 13;
        int i0 = t0 + t1 + t2 + 13;
        float c0 = b0;
        float c1 = b1 - b0;
        float c2 = b2 - b1;

        // LDS gathers: unit = gsub*55 + h + idx*2 (pair reads one 32B row)
        vf4 q0 = lp[base + i0 * 2];
        vf4 q1 = lp[base + i1 * 2];
        vf4 q2 = lp[base + i2 * 2];

        vf4 r = c0 * q0 + c1 * q1 + c2 * q2;

        // 64 lanes -> 64 consecutive float4 units: 1KB contiguous store
        __builtin_nontemporal_store(r, outb + (size_t)row * row_u);
    }
}

extern "C" void kernel_launch(void* const* d_in, const int* in_sizes, int n_in,
                              void* d_out, int out_size, void* d_ws, size_t ws_size,
                              hipStream_t stream) {
    const float* X = (const float*)d_in[0];
    const float* P = (const float*)d_in[1];
    float* out = (float*)d_out;

    const int grid = (BATCH / RT) * NCH;   // 128 * 16 = 2048
    hoact_kernel<<<grid, 256, 0, stream>>>(X, P, out);
}

// Round 10
// 33.422 us; speedup vs baseline: 1.3842x; 1.0347x over previous
//
#include <hip/hip_runtime.h>

typedef float vf4 __attribute__((ext_vector_type(4)));

#define BATCH  8192
#define GROUPS 512
#define OUT_D  8
#define GCH    32                 // groups per block
#define NCH    (GROUPS / GCH)     // 16 chunks
#define RT     64                 // batch rows per block (16 per wave)
#define RW     16                 // rows per wave
#define PQ     54                 // float4 per group in P (27*8 floats)
#define LQ     55                 // float4 per group in LDS (pad: 55%8=7 spreads bank-quads)

// R8/R9 structure (LDS-gathered params, pair-split lanes, 1KB-contiguous
// nontemporal stores) + batched X ingress: all 48 X dwords (16 rows x 3)
// are issued as one burst BEFORE the compute loop, so no per-iteration
// dependent VMEM latency remains (R9 profile: VGPR=20 -> loads were
// serialized per row with only 5 waves/SIMD of TLP to hide them).
__global__ __launch_bounds__(256) void hoact_kernel(
    const float* __restrict__ X,
    const float* __restrict__ P,
    float* __restrict__ out)
{
    __shared__ vf4 lp[GCH * LQ];       // 27.5 KB

    const int chunk = blockIdx.x % NCH;   // co-resident blocks share the chunk
    const int rt    = blockIdx.x / NCH;

    const int tid  = threadIdx.x;
    const int lane = tid & 63;
    const int w    = tid >> 6;
    const int gsub = lane >> 1;        // group within chunk 0..31
    const int h    = lane & 1;         // which 16B half of the param row

    // ---- stage params for this chunk: linear L2 read, padded LDS write ----
    const vf4* P4 = (const vf4*)P + (size_t)chunk * (GCH * PQ);
    #pragma unroll
    for (int k = 0; k < 7; ++k) {
        int m = tid + 256 * k;         // 0..1791, need < 1728
        if (m < GCH * PQ) {
            int gq = m / PQ;
            int iq = m - gq * PQ;
            lp[gq * LQ + iq] = P4[m];
        }
    }

    // ---- batched X load: 48 dwords, all independent, issued together ----
    const int g = chunk * GCH + gsub;
    const int row0 = rt * RT + w * RW;
    const float* xcol = X + (size_t)g * 3 + (size_t)row0 * (GROUPS * 3);
    float xv[RW][3];
    #pragma unroll
    for (int it = 0; it < RW; ++it) {
        const float* xp = xcol + (size_t)it * (GROUPS * 3);
        xv[it][0] = xp[0];
        xv[it][1] = xp[1];
        xv[it][2] = xp[2];
    }

    __syncthreads();

    vf4* outb = (vf4*)out + (size_t)chunk * (GCH * OUT_D / 4) + lane
              + (size_t)row0 * (GROUPS * OUT_D / 4);
    const size_t row_u = GROUPS * OUT_D / 4;     // 1024 units per out row
    const int base = gsub * LQ + h;

    #pragma unroll
    for (int it = 0; it < RW; ++it) {
        float x0 = xv[it][0], x1 = xv[it][1], x2 = xv[it][2];

        float b0 = fabsf(x0), b1 = fabsf(x1), b2 = fabsf(x2);
        int t0 = (x0 >= 0.f) ? 1 : -1;
        int t1 = (x1 >= 0.f) ? 3 : -3;
        int t2 = (x2 >= 0.f) ? 9 : -9;
        // sort ascending by |x| (ties don't affect the result)
        if (b0 > b1) { float tb=b0; b0=b1; b1=tb; int tt=t0; t0=t1; t1=tt; }
        if (b1 > b2) { float tb=b1; b1=b2; b2=tb; int tt=t1; t1=t2; t2=tt; }
        if (b0 > b1) { float tb=b0; b0=b1; b1=tb; int tt=t0; t0=t1; t1=tt; }
        int i2 = t2 + 13;
        int i1 = t1 + t2 + 13;
        int i0 = t0 + t1 + t2 + 13;
        float c0 = b0;
        float c1 = b1 - b0;
        float c2 = b2 - b1;

        // LDS gathers: unit = gsub*55 + h + idx*2 (pair reads one 32B row)
        vf4 q0 = lp[base + i0 * 2];
        vf4 q1 = lp[base + i1 * 2];
        vf4 q2 = lp[base + i2 * 2];

        vf4 r = c0 * q0 + c1 * q1 + c2 * q2;

        // 64 lanes -> 64 consecutive float4 units: 1KB contiguous store
        __builtin_nontemporal_store(r, outb + (size_t)it * row_u);
    }
}

extern "C" void kernel_launch(void* const* d_in, const int* in_sizes, int n_in,
                              void* d_out, int out_size, void* d_ws, size_t ws_size,
                              hipStream_t stream) {
    const float* X = (const float*)d_in[0];
    const float* P = (const float*)d_in[1];
    float* out = (float*)d_out;

    const int grid = (BATCH / RT) * NCH;   // 128 * 16 = 2048
    hoact_kernel<<<grid, 256, 0, stream>>>(X, P, out);
}